// Round 7
// baseline (2893.501 us; speedup 1.0000x reference)
//
#include <hip/hip_runtime.h>
#include <hip/hip_bf16.h>

// Problem constants (from reference)
#define Bq 256
#define Iq 64
#define Tq 16
#define Vq 4096
#define Eq 256
#define Hq 256
#define Gq 1024   // 4*H
#define NSEQ 16384
#define HSTR 264  // shorts per h-plane row (16B-aligned, uniform bank spread)

typedef __attribute__((ext_vector_type(8))) __bf16 bf16x8;
typedef __attribute__((ext_vector_type(4))) float f32x4;

__device__ __forceinline__ float sigf(float x) {
    return __builtin_amdgcn_rcpf(1.f + __expf(-x));
}
__device__ __forceinline__ float tanh_fast(float x) {
    float e = __expf(2.f * x);
    return 1.f - 2.f * __builtin_amdgcn_rcpf(e + 1.f);
}
__device__ __forceinline__ short bf16_rne(float x) {
    unsigned u = __float_as_uint(x);
    unsigned r = (u + 0x7fffu + ((u >> 16) & 1u)) >> 16;
    return (short)r;
}
__device__ __forceinline__ float bf16f(short h) {
    return __uint_as_float(((unsigned)(unsigned short)h) << 16);
}

// ---------------------------------------------------------------------------
// K0: fp32 gate-pack (Wih4t+b4t for k_epre; Whh4i+b4i for instr path).
// Whh4t/Wih4i slots are overwritten later by k_packB (bf16 fragments).
__global__ void k_pack(const float* __restrict__ Wih_tok,
                       const float* __restrict__ Whh_tok,
                       const float* __restrict__ Wih_ins,
                       const float* __restrict__ Whh_ins,
                       const float* __restrict__ b_tok,
                       const float* __restrict__ b_ins,
                       float* __restrict__ Wih4t, float* __restrict__ Whh4i,
                       float* __restrict__ b4t, float* __restrict__ b4i) {
    int g = blockIdx.x;          // 0..1023 original row
    int q = g >> 8;              // gate 0..3 (i,f,g,o)
    int j = g & 255;             // unit
    int k = threadIdx.x;         // 0..255
    int dst = (k * 256 + j) * 4 + q;
    Wih4t[dst] = Wih_tok[g * Hq + k];
    Whh4i[dst] = Whh_ins[g * Hq + k];
    if (k == 0) {
        b4t[j * 4 + q] = b_tok[g];
        b4i[j * 4 + q] = b_ins[g];
    }
}

// ---------------------------------------------------------------------------
// K0b: split Whh_tok / Wih_ins into bf16 hi/lo B-fragments, fragment-linear:
// element (nt, kc, lane, j) holds W[n][k] with n = nt*16+(lane&15),
// k = kc*32+(lane>>4)*8+j. A wave's tile load = one dwordx4 per lane.
__global__ void k_packB(const float* __restrict__ Whh_tok,
                        const float* __restrict__ Wih_ins,
                        short* __restrict__ Bhi, short* __restrict__ Blo,
                        short* __restrict__ BXhi, short* __restrict__ BXlo) {
    int nt = blockIdx.x;      // 0..63 n-tile
    int kc = blockIdx.y;      // 0..7  k-chunk
    int l  = threadIdx.x;     // 0..63 lane
    int n = nt * 16 + (l & 15);
    int kb = kc * 32 + (l >> 4) * 8;
    size_t ob = ((size_t)(nt * 8 + kc) * 64 + l) * 8;
    #pragma unroll
    for (int j = 0; j < 8; ++j) {
        float v = Whh_tok[n * 256 + kb + j];
        short hi = bf16_rne(v);
        Bhi[ob + j] = hi;
        Blo[ob + j] = bf16_rne(v - bf16f(hi));
        v = Wih_ins[n * 256 + kb + j];
        hi = bf16_rne(v);
        BXhi[ob + j] = hi;
        BXlo[ob + j] = bf16_rne(v - bf16f(hi));
    }
}

// ---------------------------------------------------------------------------
// K0c: counting sort of seq ids by token length, DESCENDING (longest blocks
// launch first -> better tail occupancy).
__global__ __launch_bounds__(1024) void k_sort(const int* __restrict__ tok_len,
                                               int* __restrict__ perm) {
    __shared__ int cnt[17];
    __shared__ int base[17];
    int tid = threadIdx.x;
    if (tid < 17) cnt[tid] = 0;
    __syncthreads();
    for (int i = tid; i < NSEQ; i += 1024) atomicAdd(&cnt[tok_len[i]], 1);
    __syncthreads();
    if (tid == 0) {
        int acc = 0;
        for (int b = 16; b >= 0; --b) { base[b] = acc; acc += cnt[b]; }
    }
    __syncthreads();
    for (int i = tid; i < NSEQ; i += 1024) {
        int pos = atomicAdd(&base[tok_len[i]], 1);
        perm[pos] = i;
    }
}

// ---------------------------------------------------------------------------
// K1: Epre4[v][j] = float4 gate pre-activations: emb[v,:]·W + b_tok
__global__ __launch_bounds__(256) void k_epre(const float* __restrict__ emb,
                                              const float4* __restrict__ Wih4t,
                                              const float4* __restrict__ b4t,
                                              float4* __restrict__ Ep4) {
    __shared__ float es[8][Eq];
    int tid = threadIdx.x;
    int v0 = blockIdx.x * 8;
    #pragma unroll
    for (int r = 0; r < 8; ++r) es[r][tid] = emb[(v0 + r) * Eq + tid];
    __syncthreads();
    float4 a[8];
    #pragma unroll
    for (int r = 0; r < 8; ++r) a[r] = make_float4(0.f, 0.f, 0.f, 0.f);
    const float4* Wp = Wih4t + tid;
    #pragma unroll 2
    for (int k = 0; k < Eq; ++k) {
        float4 wv = Wp[k * 256];
        #pragma unroll
        for (int r = 0; r < 8; ++r) {
            float e = es[r][k];
            a[r].x += wv.x * e; a[r].y += wv.y * e;
            a[r].z += wv.z * e; a[r].w += wv.w * e;
        }
    }
    float4 b4 = b4t[tid];
    #pragma unroll
    for (int r = 0; r < 8; ++r) {
        Ep4[(size_t)(v0 + r) * 256 + tid] =
            make_float4(a[r].x + b4.x, a[r].y + b4.y, a[r].z + b4.z, a[r].w + b4.w);
    }
}

// ---------------------------------------------------------------------------
// K2: token LSTM via MFMA 16x16x32 bf16, split-bf16 (hi/lo) for ~fp32 precision.
// 1024 blocks x 256 thr (4 waves). 16 seqs/block (M=16, one m-tile).
// Wave w owns units u in [w*64, w*64+64): n-tiles {g*16 + w*4 + q}.
// Lane holds C rows m=quad*4+r (seqs), col=lane&15 within tile.
// h double-buffered in LDS as bf16 hi/lo planes, layout [s][u]; A-frag read:
// lane reads 16B at row s=lane&15, offset k = kc*32 + quad*8  (m89/m118 layouts).
__global__ __launch_bounds__(256) void k_token_mfma(
        const int* __restrict__ tokens,      // [16384][16]
        const int* __restrict__ tok_len,     // [16384]
        const int* __restrict__ perm,        // [16384] desc-sorted seq ids
        const float4* __restrict__ Ep4,      // [V*256] gate-packed (+b_tok)
        const short* __restrict__ Bhi,       // Whh_tok hi frags
        const short* __restrict__ Blo,       // Whh_tok lo frags
        const short* __restrict__ BXhi,      // Wih_ins hi frags
        const short* __restrict__ BXlo,      // Wih_ins lo frags
        const float4* __restrict__ b4i,      // [256] gate-packed b_ins
        float* __restrict__ irepr,           // [16384][256]
        float4* __restrict__ Xp4,            // [16384*256]
        int do_xp) {
    __shared__ __align__(16) short hb[2][2][16 * HSTR];  // [buf][plane][s*HSTR+u]
    __shared__ int toks[16][Tq];
    __shared__ int lens[16];
    __shared__ int sid[16];
    int tid  = threadIdx.x;
    int w    = tid >> 6;
    int lane = tid & 63;
    int l15  = lane & 15;
    int quad = lane >> 4;
    int s0   = blockIdx.x * 16;

    if (tid < 16) {
        int q = perm[s0 + tid];
        sid[tid]  = q;
        lens[tid] = tok_len[q];
    }
    {   // zero buf 0 (both planes)
        int* hz = (int*)&hb[0][0][0];
        for (int i = tid; i < 2 * 16 * HSTR / 2; i += 256) hz[i] = 0;
    }
    __syncthreads();
    toks[tid >> 4][tid & 15] = tokens[sid[tid >> 4] * Tq + (tid & 15)];
    int lenr[4];
    #pragma unroll
    for (int r = 0; r < 4; ++r) lenr[r] = lens[quad * 4 + r];
    int tmax = 0;
    #pragma unroll
    for (int s = 0; s < 16; ++s) tmax = max(tmax, lens[s]);
    __syncthreads();

    f32x4 acc[4][4];   // [gate][q-subtile]; elem r = seq quad*4+r
    float cst[4][4], hst[4][4];
    #pragma unroll
    for (int q = 0; q < 4; ++q)
        #pragma unroll
        for (int r = 0; r < 4; ++r) { cst[q][r] = 0.f; hst[q][r] = 0.f; }
    int ubase = w * 64;

    for (int t = 0; t < tmax; ++t) {
        // C init from Epre gather (includes b_tok)
        #pragma unroll
        for (int q = 0; q < 4; ++q) {
            int u = ubase + q * 16 + l15;
            #pragma unroll
            for (int r = 0; r < 4; ++r) {
                float4 e = Ep4[(size_t)toks[quad * 4 + r][t] * 256 + u];
                acc[0][q][r] = e.x; acc[1][q][r] = e.y;
                acc[2][q][r] = e.z; acc[3][q][r] = e.w;
            }
        }
        const short* hc0 = &hb[t & 1][0][l15 * HSTR];
        const short* hc1 = &hb[t & 1][1][l15 * HSTR];
        #pragma unroll
        for (int kc = 0; kc < 8; ++kc) {
            bf16x8 ahi = *(const bf16x8*)(hc0 + kc * 32 + quad * 8);
            bf16x8 alo = *(const bf16x8*)(hc1 + kc * 32 + quad * 8);
            #pragma unroll
            for (int g = 0; g < 4; ++g) {
                #pragma unroll
                for (int q = 0; q < 4; ++q) {
                    int nt = g * 16 + w * 4 + q;
                    size_t bi = ((size_t)(nt * 8 + kc) * 64 + lane) * 8;
                    bf16x8 bh = *(const bf16x8*)(Bhi + bi);
                    bf16x8 bl = *(const bf16x8*)(Blo + bi);
                    acc[g][q] = __builtin_amdgcn_mfma_f32_16x16x32_bf16(ahi, bh, acc[g][q], 0, 0, 0);
                    acc[g][q] = __builtin_amdgcn_mfma_f32_16x16x32_bf16(alo, bh, acc[g][q], 0, 0, 0);
                    acc[g][q] = __builtin_amdgcn_mfma_f32_16x16x32_bf16(ahi, bl, acc[g][q], 0, 0, 0);
                }
            }
        }
        // elementwise update; ALWAYS rewrite h (keeps frozen seqs correct in dbuf)
        short* hn0 = &hb[(t + 1) & 1][0][0];
        short* hn1 = &hb[(t + 1) & 1][1][0];
        #pragma unroll
        for (int q = 0; q < 4; ++q) {
            int u = ubase + q * 16 + l15;
            #pragma unroll
            for (int r = 0; r < 4; ++r) {
                int s = quad * 4 + r;
                if (t < lenr[r]) {
                    float cn = sigf(acc[1][q][r]) * cst[q][r]
                             + sigf(acc[0][q][r]) * tanh_fast(acc[2][q][r]);
                    cst[q][r] = cn;
                    hst[q][r] = sigf(acc[3][q][r]) * tanh_fast(cn);
                }
                float hv = hst[q][r];
                short hi = bf16_rne(hv);
                hn0[s * HSTR + u] = hi;
                hn1[s * HSTR + u] = bf16_rne(hv - bf16f(hi));
            }
        }
        __syncthreads();
    }

    #pragma unroll
    for (int q = 0; q < 4; ++q) {
        int u = ubase + q * 16 + l15;
        #pragma unroll
        for (int r = 0; r < 4; ++r)
            irepr[(size_t)sid[quad * 4 + r] * 256 + u] = hst[q][r];
    }

    if (do_xp) {
        // Xp[s] = Wih_ins · h_final + b_ins (one extra MFMA pass)
        #pragma unroll
        for (int q = 0; q < 4; ++q) {
            float4 bb = b4i[ubase + q * 16 + l15];
            #pragma unroll
            for (int r = 0; r < 4; ++r) {
                acc[0][q][r] = bb.x; acc[1][q][r] = bb.y;
                acc[2][q][r] = bb.z; acc[3][q][r] = bb.w;
            }
        }
        const short* hc0 = &hb[tmax & 1][0][l15 * HSTR];
        const short* hc1 = &hb[tmax & 1][1][l15 * HSTR];
        #pragma unroll
        for (int kc = 0; kc < 8; ++kc) {
            bf16x8 ahi = *(const bf16x8*)(hc0 + kc * 32 + quad * 8);
            bf16x8 alo = *(const bf16x8*)(hc1 + kc * 32 + quad * 8);
            #pragma unroll
            for (int g = 0; g < 4; ++g) {
                #pragma unroll
                for (int q = 0; q < 4; ++q) {
                    int nt = g * 16 + w * 4 + q;
                    size_t bi = ((size_t)(nt * 8 + kc) * 64 + lane) * 8;
                    bf16x8 bh = *(const bf16x8*)(BXhi + bi);
                    bf16x8 bl = *(const bf16x8*)(BXlo + bi);
                    acc[g][q] = __builtin_amdgcn_mfma_f32_16x16x32_bf16(ahi, bh, acc[g][q], 0, 0, 0);
                    acc[g][q] = __builtin_amdgcn_mfma_f32_16x16x32_bf16(alo, bh, acc[g][q], 0, 0, 0);
                    acc[g][q] = __builtin_amdgcn_mfma_f32_16x16x32_bf16(ahi, bl, acc[g][q], 0, 0, 0);
                }
            }
        }
        #pragma unroll
        for (int q = 0; q < 4; ++q) {
            int u = ubase + q * 16 + l15;
            #pragma unroll
            for (int r = 0; r < 4; ++r) {
                Xp4[(size_t)sid[quad * 4 + r] * 256 + u] =
                    make_float4(acc[0][q][r], acc[1][q][r], acc[2][q][r], acc[3][q][r]);
            }
        }
    }
}

// ---------------------------------------------------------------------------
// K3: instr LSTM, 256 blocks x 256 thr, 1 seq/block, K=256, Xp4 precomputed.
#define FMA4(acc, wv4, hh) \
    acc.x += (wv4).x * (hh); acc.y += (wv4).y * (hh); \
    acc.z += (wv4).z * (hh); acc.w += (wv4).w * (hh);

__global__ __launch_bounds__(256) void k_instr_fused(
        const float4* __restrict__ Xp4,        // [16384*256] gate-packed
        const int* __restrict__ instr_cnt,     // [256]
        const float4* __restrict__ Whh4i,      // [256*256] gate-packed
        const float* __restrict__ linW,        // [256]
        const float* __restrict__ linb,        // [1]
        float* __restrict__ out) {             // [256]
    __shared__ __align__(16) float hsl[Hq];
    __shared__ float red[4];
    int tid = threadIdx.x;
    int b = blockIdx.x;
    int len = instr_cnt[b];
    hsl[tid] = 0.f;
    float cc = 0.f;
    float4 xcur = Xp4[(size_t)b * Iq * 256 + tid];
    __syncthreads();

    for (int i = 0; i < len; ++i) {
        float4 acc = xcur;
        float4 xn = xcur;
        if (i + 1 < len) xn = Xp4[((size_t)b * Iq + i + 1) * 256 + tid];
        const float4* Wh = Whh4i + tid;
        const float4* hp = (const float4*)hsl;
        #pragma unroll 4
        for (int k4 = 0; k4 < Hq / 4; ++k4) {
            float4 h4 = hp[k4];
            float4 w0 = Wh[(k4 * 4 + 0) * 256];
            float4 w1 = Wh[(k4 * 4 + 1) * 256];
            float4 w2 = Wh[(k4 * 4 + 2) * 256];
            float4 w3 = Wh[(k4 * 4 + 3) * 256];
            FMA4(acc, w0, h4.x) FMA4(acc, w1, h4.y)
            FMA4(acc, w2, h4.z) FMA4(acc, w3, h4.w)
        }
        __syncthreads();  // done reading hsl
        float cn = sigf(acc.y) * cc + sigf(acc.x) * tanh_fast(acc.z);
        cc = cn;
        hsl[tid] = sigf(acc.w) * tanh_fast(cn);
        xcur = xn;
        __syncthreads();  // hsl visible
    }

    float p = linW[tid] * hsl[tid];
    #pragma unroll
    for (int off = 32; off > 0; off >>= 1) p += __shfl_down(p, off);
    if ((tid & 63) == 0) red[tid >> 6] = p;
    __syncthreads();
    if (tid == 0) out[b] = red[0] + red[1] + red[2] + red[3] + linb[0];
}

// ---------------------------------------------------------------------------
extern "C" void kernel_launch(void* const* d_in, const int* in_sizes, int n_in,
                              void* d_out, int out_size, void* d_ws, size_t ws_size,
                              hipStream_t stream) {
    const int*   tokens  = (const int*)d_in[0];
    const int*   icnt    = (const int*)d_in[1];
    const int*   tcnt    = (const int*)d_in[2];
    const float* emb     = (const float*)d_in[3];
    const float* Wih_tok = (const float*)d_in[4];
    const float* Whh_tok = (const float*)d_in[5];
    const float* b_tok   = (const float*)d_in[6];
    const float* Wih_ins = (const float*)d_in[7];
    const float* Whh_ins = (const float*)d_in[8];
    const float* b_ins   = (const float*)d_in[9];
    const float* linW    = (const float*)d_in[10];
    const float* linb    = (const float*)d_in[11];
    float* out = (float*)d_out;

    float* ws = (float*)d_ws;
    float* Wih4t = ws;                    // 262144 fp32 (k_epre)
    float* Bslot = Wih4t + 262144;        // 262144 fp32 -> Bhi,Blo (bf16 frags)
    float* BXslot= Bslot + 262144;        // 262144 fp32 -> BXhi,BXlo
    float* Whh4i = BXslot + 262144;       // 262144 fp32 (instr path)
    float* b4t   = Whh4i + 262144;        // 1024
    float* b4i   = b4t + 1024;            // 1024
    int*   perm  = (int*)(b4i + 1024);    // 16384
    float* Ep4   = b4i + 1024 + 16384;    // 4194304
    float* irepr = Ep4 + 4194304;         // 4194304
    float* Xp4   = irepr + 4194304;       // 16777216

    short* Bhi  = (short*)Bslot;          // 262144 bf16
    short* Blo  = Bhi + 262144;
    short* BXhi = (short*)BXslot;
    short* BXlo = BXhi + 262144;

    size_t need = (size_t)(262144 * 4 + 2048 + 16384 + 4194304 * 2 + 16777216) * 4;
    if (ws_size < need) return;  // fail loudly

    hipLaunchKernelGGL(k_pack, dim3(1024), dim3(256), 0, stream,
                       Wih_tok, Whh_tok, Wih_ins, Whh_ins, b_tok, b_ins,
                       Wih4t, Whh4i, b4t, b4i);
    hipLaunchKernelGGL(k_packB, dim3(64, 8), dim3(64), 0, stream,
                       Whh_tok, Wih_ins, Bhi, Blo, BXhi, BXlo);
    hipLaunchKernelGGL(k_sort, dim3(1), dim3(1024), 0, stream, tcnt, perm);
    hipLaunchKernelGGL(k_epre, dim3(512), dim3(256), 0, stream,
                       emb, (const float4*)Wih4t, (const float4*)b4t, (float4*)Ep4);
    hipLaunchKernelGGL(k_token_mfma, dim3(1024), dim3(256), 0, stream,
                       tokens, tcnt, perm, (const float4*)Ep4,
                       Bhi, Blo, BXhi, BXlo, (const float4*)b4i,
                       irepr, (float4*)Xp4, 1);
    hipLaunchKernelGGL(k_instr_fused, dim3(256), dim3(256), 0, stream,
                       (const float4*)Xp4, icnt, (const float4*)Whh4i,
                       linW, linb, out);
}

// Round 8
// 1707.264 us; speedup vs baseline: 1.6948x; 1.6948x over previous
//
#include <hip/hip_runtime.h>
#include <hip/hip_bf16.h>

// Problem constants (from reference)
#define Bq 256
#define Iq 64
#define Tq 16
#define Vq 4096
#define Eq 256
#define Hq 256
#define NSEQ 16384
#define HSTR 264  // shorts per h-plane row (16B-aligned)

typedef __attribute__((ext_vector_type(8))) __bf16 bf16x8;
typedef __attribute__((ext_vector_type(4))) float f32x4;

__device__ __forceinline__ float sigf(float x) {
    return __builtin_amdgcn_rcpf(1.f + __expf(-x));
}
__device__ __forceinline__ float tanh_fast(float x) {
    float e = __expf(2.f * x);
    return 1.f - 2.f * __builtin_amdgcn_rcpf(e + 1.f);
}
__device__ __forceinline__ short bf16_rne(float x) {
    unsigned u = __float_as_uint(x);
    unsigned r = (u + 0x7fffu + ((u >> 16) & 1u)) >> 16;
    return (short)r;
}
__device__ __forceinline__ float bf16f(short h) {
    return __uint_as_float(((unsigned)(unsigned short)h) << 16);
}

// ---------------------------------------------------------------------------
// K0: gate-pack Wih_tok (fp32, for k_epre) + biases.
__global__ void k_pack(const float* __restrict__ Wih_tok,
                       const float* __restrict__ b_tok,
                       const float* __restrict__ b_ins,
                       float* __restrict__ Wih4t,
                       float* __restrict__ b4t, float* __restrict__ b4i) {
    int g = blockIdx.x;          // 0..1023 original row
    int q = g >> 8;              // gate 0..3 (i,f,g,o)
    int j = g & 255;             // unit
    int k = threadIdx.x;         // 0..255
    Wih4t[(k * 256 + j) * 4 + q] = Wih_tok[g * Hq + k];
    if (k == 0) {
        b4t[j * 4 + q] = b_tok[g];
        b4i[j * 4 + q] = b_ins[g];
    }
}

// ---------------------------------------------------------------------------
// K0b: split 3 weight matrices into bf16 hi/lo B-fragments, fragment-linear:
// element (nt, kc, lane, j) holds W[n][k], n = nt*16+(lane&15),
// k = kc*32+(lane>>4)*8+j. One dwordx4 per lane per tile. (Layout verified R7.)
__global__ void k_packB(const float* __restrict__ W0,   // Whh_tok
                        const float* __restrict__ W1,   // Wih_ins
                        const float* __restrict__ W2,   // Whh_ins
                        short* __restrict__ B0h, short* __restrict__ B0l,
                        short* __restrict__ B1h, short* __restrict__ B1l,
                        short* __restrict__ B2h, short* __restrict__ B2l) {
    int nt = blockIdx.x;      // 0..63 n-tile
    int kc = blockIdx.y;      // 0..7  k-chunk
    int l  = threadIdx.x;     // 0..63 lane
    int n = nt * 16 + (l & 15);
    int kb = kc * 32 + (l >> 4) * 8;
    size_t ob = ((size_t)(nt * 8 + kc) * 64 + l) * 8;
    #pragma unroll
    for (int j = 0; j < 8; ++j) {
        float v = W0[n * 256 + kb + j];
        short hi = bf16_rne(v);
        B0h[ob + j] = hi; B0l[ob + j] = bf16_rne(v - bf16f(hi));
        v = W1[n * 256 + kb + j];
        hi = bf16_rne(v);
        B1h[ob + j] = hi; B1l[ob + j] = bf16_rne(v - bf16f(hi));
        v = W2[n * 256 + kb + j];
        hi = bf16_rne(v);
        B2h[ob + j] = hi; B2l[ob + j] = bf16_rne(v - bf16f(hi));
    }
}

// ---------------------------------------------------------------------------
// K0c: counting sort by length, DESCENDING. Generic (n, nbins<=65), 1 block.
__global__ __launch_bounds__(1024) void k_sortn(const int* __restrict__ len,
                                                int* __restrict__ perm,
                                                int n, int nbins) {
    __shared__ int cnt[65];
    __shared__ int base[65];
    int tid = threadIdx.x;
    if (tid < nbins) cnt[tid] = 0;
    __syncthreads();
    for (int i = tid; i < n; i += 1024) atomicAdd(&cnt[len[i]], 1);
    __syncthreads();
    if (tid == 0) {
        int acc = 0;
        for (int b = nbins - 1; b >= 0; --b) { base[b] = acc; acc += cnt[b]; }
    }
    __syncthreads();
    for (int i = tid; i < n; i += 1024) {
        int pos = atomicAdd(&base[len[i]], 1);
        perm[pos] = i;
    }
}

// ---------------------------------------------------------------------------
// K1: Epre4[v][j] = float4 gate pre-activations: emb[v,:]·W + b_tok
__global__ __launch_bounds__(256) void k_epre(const float* __restrict__ emb,
                                              const float4* __restrict__ Wih4t,
                                              const float4* __restrict__ b4t,
                                              float4* __restrict__ Ep4) {
    __shared__ float es[8][Eq];
    int tid = threadIdx.x;
    int v0 = blockIdx.x * 8;
    #pragma unroll
    for (int r = 0; r < 8; ++r) es[r][tid] = emb[(v0 + r) * Eq + tid];
    __syncthreads();
    float4 a[8];
    #pragma unroll
    for (int r = 0; r < 8; ++r) a[r] = make_float4(0.f, 0.f, 0.f, 0.f);
    const float4* Wp = Wih4t + tid;
    #pragma unroll 2
    for (int k = 0; k < Eq; ++k) {
        float4 wv = Wp[k * 256];
        #pragma unroll
        for (int r = 0; r < 8; ++r) {
            float e = es[r][k];
            a[r].x += wv.x * e; a[r].y += wv.y * e;
            a[r].z += wv.z * e; a[r].w += wv.w * e;
        }
    }
    float4 b4 = b4t[tid];
    #pragma unroll
    for (int r = 0; r < 8; ++r) {
        Ep4[(size_t)(v0 + r) * 256 + tid] =
            make_float4(a[r].x + b4.x, a[r].y + b4.y, a[r].z + b4.z, a[r].w + b4.w);
    }
}

// ---------------------------------------------------------------------------
// Shared MFMA tile body: for one kc, A-frags from LDS, 16 tiles (4g x 4q),
// 3 split-bf16 MFMAs each. kc loop is runtime (unroll 1) so B-loads cannot
// hoist across iterations (R7 spilled from 256 in-flight loads).
#define MFMA_KC_BODY(BH, BL) { \
    bf16x8 ahi = *(const bf16x8*)(hc0 + kc * 32 + quad * 8); \
    bf16x8 alo = *(const bf16x8*)(hc1 + kc * 32 + quad * 8); \
    const short* bhb = (BH) + (size_t)(w * 4 * 8 + kc) * 512 + lane * 8; \
    const short* blb = (BL) + (size_t)(w * 4 * 8 + kc) * 512 + lane * 8; \
    _Pragma("unroll") \
    for (int g = 0; g < 4; ++g) { \
        _Pragma("unroll") \
        for (int q = 0; q < 4; ++q) { \
            bf16x8 bh = *(const bf16x8*)(bhb + g * 65536 + q * 4096); \
            bf16x8 bl = *(const bf16x8*)(blb + g * 65536 + q * 4096); \
            acc[g][q] = __builtin_amdgcn_mfma_f32_16x16x32_bf16(ahi, bh, acc[g][q], 0, 0, 0); \
            acc[g][q] = __builtin_amdgcn_mfma_f32_16x16x32_bf16(alo, bh, acc[g][q], 0, 0, 0); \
            acc[g][q] = __builtin_amdgcn_mfma_f32_16x16x32_bf16(ahi, bl, acc[g][q], 0, 0, 0); \
        } \
    } }

// ---------------------------------------------------------------------------
// K2: token LSTM via MFMA 16x16x32 bf16 split-hi/lo. 1024 blocks x 256 thr,
// 16 sorted seqs/block. Writes only Xp4 = Wih_ins·h_final + b_ins.
__global__ __launch_bounds__(256) void k_token_mfma(
        const int* __restrict__ tokens,      // [16384][16]
        const int* __restrict__ tok_len,     // [16384]
        const int* __restrict__ perm,        // [16384] desc-sorted
        const float4* __restrict__ Ep4,      // [V*256] gate-packed (+b_tok)
        const short* __restrict__ Bhi, const short* __restrict__ Blo,   // Whh_tok
        const short* __restrict__ BXhi, const short* __restrict__ BXlo, // Wih_ins
        const float4* __restrict__ b4i,      // [256] gate-packed b_ins
        float4* __restrict__ Xp4) {          // [16384*256]
    __shared__ __align__(16) short hb[2][2][16 * HSTR];  // [buf][plane][s*HSTR+u]
    __shared__ int toks[16][Tq];
    __shared__ int lens[16];
    __shared__ int sid[16];
    int tid  = threadIdx.x;
    int w    = tid >> 6;
    int lane = tid & 63;
    int l15  = lane & 15;
    int quad = lane >> 4;
    int s0   = blockIdx.x * 16;

    if (tid < 16) {
        int q = perm[s0 + tid];
        sid[tid]  = q;
        lens[tid] = tok_len[q];
    }
    {
        int* hz = (int*)&hb[0][0][0];
        for (int i = tid; i < 16 * HSTR; i += 256) hz[i] = 0;
    }
    __syncthreads();
    toks[tid >> 4][tid & 15] = tokens[sid[tid >> 4] * Tq + (tid & 15)];
    int lenr[4];
    #pragma unroll
    for (int r = 0; r < 4; ++r) lenr[r] = lens[quad * 4 + r];
    int tmax = 0;
    #pragma unroll
    for (int s = 0; s < 16; ++s) tmax = max(tmax, lens[s]);
    __syncthreads();

    f32x4 acc[4][4];   // [gate][q]; elem r = seq quad*4+r
    float cst[4][4], hst[4][4];
    #pragma unroll
    for (int q = 0; q < 4; ++q)
        #pragma unroll
        for (int r = 0; r < 4; ++r) { cst[q][r] = 0.f; hst[q][r] = 0.f; }
    int ubase = w * 64;

    for (int t = 0; t < tmax; ++t) {
        #pragma unroll
        for (int q = 0; q < 4; ++q) {
            int u = ubase + q * 16 + l15;
            #pragma unroll
            for (int r = 0; r < 4; ++r) {
                float4 e = Ep4[(size_t)toks[quad * 4 + r][t] * 256 + u];
                acc[0][q][r] = e.x; acc[1][q][r] = e.y;
                acc[2][q][r] = e.z; acc[3][q][r] = e.w;
            }
        }
        const short* hc0 = &hb[t & 1][0][l15 * HSTR];
        const short* hc1 = &hb[t & 1][1][l15 * HSTR];
        #pragma unroll 1
        for (int kc = 0; kc < 8; ++kc) MFMA_KC_BODY(Bhi, Blo)
        short* hn0 = &hb[(t + 1) & 1][0][0];
        short* hn1 = &hb[(t + 1) & 1][1][0];
        #pragma unroll
        for (int q = 0; q < 4; ++q) {
            int u = ubase + q * 16 + l15;
            #pragma unroll
            for (int r = 0; r < 4; ++r) {
                int s = quad * 4 + r;
                if (t < lenr[r]) {
                    float cn = sigf(acc[1][q][r]) * cst[q][r]
                             + sigf(acc[0][q][r]) * tanh_fast(acc[2][q][r]);
                    cst[q][r] = cn;
                    hst[q][r] = sigf(acc[3][q][r]) * tanh_fast(cn);
                }
                float hv = hst[q][r];
                short hi = bf16_rne(hv);
                hn0[s * HSTR + u] = hi;
                hn1[s * HSTR + u] = bf16_rne(hv - bf16f(hi));
            }
        }
        __syncthreads();
    }

    // Xp = Wih_ins · h_final + b_ins
    #pragma unroll
    for (int q = 0; q < 4; ++q) {
        float4 bb = b4i[ubase + q * 16 + l15];
        #pragma unroll
        for (int r = 0; r < 4; ++r) {
            acc[0][q][r] = bb.x; acc[1][q][r] = bb.y;
            acc[2][q][r] = bb.z; acc[3][q][r] = bb.w;
        }
    }
    {
        const short* hc0 = &hb[tmax & 1][0][l15 * HSTR];
        const short* hc1 = &hb[tmax & 1][1][l15 * HSTR];
        #pragma unroll 1
        for (int kc = 0; kc < 8; ++kc) MFMA_KC_BODY(BXhi, BXlo)
    }
    #pragma unroll
    for (int q = 0; q < 4; ++q) {
        int u = ubase + q * 16 + l15;
        #pragma unroll
        for (int r = 0; r < 4; ++r) {
            Xp4[(size_t)sid[quad * 4 + r] * 256 + u] =
                make_float4(acc[0][q][r], acc[1][q][r], acc[2][q][r], acc[3][q][r]);
        }
    }
}

// ---------------------------------------------------------------------------
// K3: instr LSTM via the same MFMA structure. 16 blocks x 256 thr,
// 16 icnt-sorted seqs/block, up to 64 steps. C-init gathers Xp4 (has b_ins).
// Fused final linear: out[seq] = linW·h + linb.
__global__ __launch_bounds__(256) void k_instr_mfma(
        const float4* __restrict__ Xp4,      // [256*64][256] gate-packed
        const int* __restrict__ instr_cnt,   // [256]
        const int* __restrict__ perm2,       // [256] desc-sorted
        const short* __restrict__ BHhi, const short* __restrict__ BHlo, // Whh_ins
        const float* __restrict__ linW,      // [256]
        const float* __restrict__ linb,      // [1]
        float* __restrict__ out) {           // [256]
    __shared__ __align__(16) short hb[2][2][16 * HSTR];
    __shared__ int lens[16];
    __shared__ int sid[16];
    __shared__ float hsf[16][272];
    int tid  = threadIdx.x;
    int w    = tid >> 6;
    int lane = tid & 63;
    int l15  = lane & 15;
    int quad = lane >> 4;
    int s0   = blockIdx.x * 16;

    if (tid < 16) {
        int q = perm2[s0 + tid];
        sid[tid]  = q;
        lens[tid] = instr_cnt[q];
    }
    {
        int* hz = (int*)&hb[0][0][0];
        for (int i = tid; i < 16 * HSTR; i += 256) hz[i] = 0;
    }
    __syncthreads();
    int lenr[4], sidr[4];
    #pragma unroll
    for (int r = 0; r < 4; ++r) { lenr[r] = lens[quad * 4 + r]; sidr[r] = sid[quad * 4 + r]; }
    int tmax = 0;
    #pragma unroll
    for (int s = 0; s < 16; ++s) tmax = max(tmax, lens[s]);

    f32x4 acc[4][4];
    float cst[4][4], hst[4][4];
    #pragma unroll
    for (int q = 0; q < 4; ++q)
        #pragma unroll
        for (int r = 0; r < 4; ++r) { cst[q][r] = 0.f; hst[q][r] = 0.f; }
    int ubase = w * 64;

    for (int t = 0; t < tmax; ++t) {
        #pragma unroll
        for (int q = 0; q < 4; ++q) {
            int u = ubase + q * 16 + l15;
            #pragma unroll
            for (int r = 0; r < 4; ++r) {
                float4 e = Xp4[((size_t)sidr[r] * Iq + t) * 256 + u];
                acc[0][q][r] = e.x; acc[1][q][r] = e.y;
                acc[2][q][r] = e.z; acc[3][q][r] = e.w;
            }
        }
        const short* hc0 = &hb[t & 1][0][l15 * HSTR];
        const short* hc1 = &hb[t & 1][1][l15 * HSTR];
        #pragma unroll 1
        for (int kc = 0; kc < 8; ++kc) MFMA_KC_BODY(BHhi, BHlo)
        short* hn0 = &hb[(t + 1) & 1][0][0];
        short* hn1 = &hb[(t + 1) & 1][1][0];
        #pragma unroll
        for (int q = 0; q < 4; ++q) {
            int u = ubase + q * 16 + l15;
            #pragma unroll
            for (int r = 0; r < 4; ++r) {
                int s = quad * 4 + r;
                if (t < lenr[r]) {
                    float cn = sigf(acc[1][q][r]) * cst[q][r]
                             + sigf(acc[0][q][r]) * tanh_fast(acc[2][q][r]);
                    cst[q][r] = cn;
                    hst[q][r] = sigf(acc[3][q][r]) * tanh_fast(cn);
                }
                float hv = hst[q][r];
                short hi = bf16_rne(hv);
                hn0[s * HSTR + u] = hi;
                hn1[s * HSTR + u] = bf16_rne(hv - bf16f(hi));
            }
        }
        __syncthreads();
    }

    // final linear: stage h (fp32) to LDS, 16 threads per seq reduce 256 units
    #pragma unroll
    for (int q = 0; q < 4; ++q) {
        int u = ubase + q * 16 + l15;
        #pragma unroll
        for (int r = 0; r < 4; ++r) hsf[quad * 4 + r][u] = hst[q][r];
    }
    __syncthreads();
    int s = tid >> 4, u0 = tid & 15;
    float p = 0.f;
    #pragma unroll
    for (int j = 0; j < 16; ++j) p += linW[u0 + j * 16] * hsf[s][u0 + j * 16];
    p += __shfl_down(p, 8, 16);
    p += __shfl_down(p, 4, 16);
    p += __shfl_down(p, 2, 16);
    p += __shfl_down(p, 1, 16);
    if (u0 == 0) out[sid[s]] = p + linb[0];
}

// ---------------------------------------------------------------------------
extern "C" void kernel_launch(void* const* d_in, const int* in_sizes, int n_in,
                              void* d_out, int out_size, void* d_ws, size_t ws_size,
                              hipStream_t stream) {
    const int*   tokens  = (const int*)d_in[0];
    const int*   icnt    = (const int*)d_in[1];
    const int*   tcnt    = (const int*)d_in[2];
    const float* emb     = (const float*)d_in[3];
    const float* Wih_tok = (const float*)d_in[4];
    const float* Whh_tok = (const float*)d_in[5];
    const float* b_tok   = (const float*)d_in[6];
    const float* Wih_ins = (const float*)d_in[7];
    const float* Whh_ins = (const float*)d_in[8];
    const float* b_ins   = (const float*)d_in[9];
    const float* linW    = (const float*)d_in[10];
    const float* linb    = (const float*)d_in[11];
    float* out = (float*)d_out;

    float* ws_f  = (float*)d_ws;
    float* Wih4t = ws_f;                     // 262144 f
    float* b4t   = Wih4t + 262144;           // 1024 f
    float* b4i   = b4t + 1024;               // 1024 f
    int*   perm  = (int*)(b4i + 1024);       // 16384 i
    int*   perm2 = perm + 16384;             // 256 i
    short* Bhi   = (short*)(perm2 + 256);    // 6 x 262144 shorts
    short* Blo   = Bhi + 262144;
    short* BXhi  = Blo + 262144;
    short* BXlo  = BXhi + 262144;
    short* BHhi  = BXlo + 262144;
    short* BHlo  = BHhi + 262144;
    float* Ep4   = (float*)(BHlo + 262144);  // 4194304 f
    float* Xp4   = Ep4 + 4194304;            // 16777216 f

    size_t need = 4269056 + (size_t)(4194304 + 16777216) * 4;
    if (ws_size < need) return;  // fail loudly

    hipLaunchKernelGGL(k_pack, dim3(1024), dim3(256), 0, stream,
                       Wih_tok, b_tok, b_ins, Wih4t, b4t, b4i);
    hipLaunchKernelGGL(k_packB, dim3(64, 8), dim3(64), 0, stream,
                       Whh_tok, Wih_ins, Whh_ins, Bhi, Blo, BXhi, BXlo, BHhi, BHlo);
    hipLaunchKernelGGL(k_sortn, dim3(1), dim3(1024), 0, stream, tcnt, perm, NSEQ, 17);
    hipLaunchKernelGGL(k_sortn, dim3(1), dim3(1024), 0, stream, icnt, perm2, Bq, 65);
    hipLaunchKernelGGL(k_epre, dim3(512), dim3(256), 0, stream,
                       emb, (const float4*)Wih4t, (const float4*)b4t, (float4*)Ep4);
    hipLaunchKernelGGL(k_token_mfma, dim3(1024), dim3(256), 0, stream,
                       tokens, tcnt, perm, (const float4*)Ep4,
                       Bhi, Blo, BXhi, BXlo, (const float4*)b4i, (float4*)Xp4);
    hipLaunchKernelGGL(k_instr_mfma, dim3(16), dim3(256), 0, stream,
                       (const float4*)Xp4, icnt, perm2, BHhi, BHlo,
                       linW, linb, out);
}